// Round 1
// baseline (188.261 us; speedup 1.0000x reference)
//
#include <hip/hip_runtime.h>
#include <cstdint>
#include <cstddef>

// Problem constants
#define BB 32
#define SS 512
#define HH 768
#define WW 256
#define LL 8
#define NINTENT 26
#define NSLOT 121

typedef float f32x4 __attribute__((ext_vector_type(4)));
typedef __bf16 bf16x8 __attribute__((ext_vector_type(8)));

static __device__ __forceinline__ float bf2f(unsigned short u) {
    union { unsigned int i; float f; } x; x.i = ((unsigned int)u) << 16; return x.f;
}
static __device__ __forceinline__ unsigned short f2bf(float f) {
    union { float f; unsigned int i; } x; x.f = f;
    unsigned int r = (x.i + 0x7fffu + ((x.i >> 16) & 1u)) >> 16;
    return (unsigned short)r;
}

// ---------------- cast kernels ----------------
__global__ __launch_bounds__(256) void cast_f32_bf16(const float4* __restrict__ src,
                                                     ushort4* __restrict__ dst, int n4) {
    int stride = gridDim.x * blockDim.x;
    for (int i = blockIdx.x * blockDim.x + threadIdx.x; i < n4; i += stride) {
        float4 v = src[i];
        ushort4 o;
        o.x = f2bf(v.x); o.y = f2bf(v.y); o.z = f2bf(v.z); o.w = f2bf(v.w);
        dst[i] = o;
    }
}

__global__ __launch_bounds__(256) void cast_slotw(const float* __restrict__ w,
                                                  unsigned short* __restrict__ dst) {
    int i = blockIdx.x * blockDim.x + threadIdx.x;
    if (i < 128 * HH) {
        int r = i / HH;
        dst[i] = (r < NSLOT) ? f2bf(w[i]) : (unsigned short)0;
    }
}

__global__ __launch_bounds__(256) void build_biascat(const float* __restrict__ bq,
                                                     const float* __restrict__ bk,
                                                     const float* __restrict__ bv,
                                                     float* __restrict__ out) {
    int i = blockIdx.x * blockDim.x + threadIdx.x;
    if (i < HH) { out[i] = bq[i]; out[i + HH] = bk[i]; out[i + 2 * HH] = bv[i]; }
}

// ---------------- GEMM: C[M][N] = A[M][K] * Bm[N][K]^T ----------------
// A, Bm row-major bf16 (as uint4 = 8 bf16). 128x128 tile, BK=32, 4 waves (2x2),
// each wave 64x64 via 4x4 fragments of mfma_f32_16x16x32_bf16.
template <bool SLOT>
__global__ __launch_bounds__(256) void gemm128(
    const uint4* __restrict__ A,    // [M][K/8]
    const uint4* __restrict__ Bm,   // [NT*128][K/8]
    const float* __restrict__ bias, // [N] (qkv) or [121] (slot)
    unsigned short* __restrict__ Cb,// bf16 out [M][NT*128]   (qkv path)
    float* __restrict__ Cf,         // f32 out, ld=121        (slot path)
    int NT, int K)
{
    __shared__ uint4 sA[512];   // 128 rows x 32 bf16
    __shared__ uint4 sB[512];
    const int K8 = K >> 3;      // 96

    int bid = blockIdx.x;
    int mt = bid / NT, nt = bid % NT;
    int t = threadIdx.x;
    int lane = t & 63, wave = t >> 6;
    int wm = wave >> 1, wn = wave & 1;
    int l16 = lane & 15, lk = lane >> 4;

    int r = t >> 2, kc = t & 3;   // staging: row r, 16B chunk kc
    const uint4* Arow = A + (size_t)(mt * 128 + r) * K8 + kc;
    const uint4* Brow = Bm + (size_t)(nt * 128 + r) * K8 + kc;

    f32x4 zero = {0.f, 0.f, 0.f, 0.f};
    f32x4 acc[4][4];
#pragma unroll
    for (int i = 0; i < 4; i++)
#pragma unroll
        for (int j = 0; j < 4; j++) acc[i][j] = zero;

    for (int k0 = 0; k0 < K8; k0 += 4) {
        sA[t]       = Arow[k0];
        sA[t + 256] = Arow[k0 + (size_t)64 * K8];
        sB[t]       = Brow[k0];
        sB[t + 256] = Brow[k0 + (size_t)64 * K8];
        __syncthreads();

        bf16x8 af[4], bfr[4];
#pragma unroll
        for (int i = 0; i < 4; i++) {
            int m = wm * 64 + i * 16 + l16;
            af[i] = *reinterpret_cast<const bf16x8*>(&sA[m * 4 + lk]);
        }
#pragma unroll
        for (int j = 0; j < 4; j++) {
            int n = wn * 64 + j * 16 + l16;
            bfr[j] = *reinterpret_cast<const bf16x8*>(&sB[n * 4 + lk]);
        }
#pragma unroll
        for (int i = 0; i < 4; i++)
#pragma unroll
            for (int j = 0; j < 4; j++)
                acc[i][j] = __builtin_amdgcn_mfma_f32_16x16x32_bf16(af[i], bfr[j], acc[i][j], 0, 0, 0);
        __syncthreads();
    }

    const int N = NT * 128;
#pragma unroll
    for (int i = 0; i < 4; i++) {
#pragma unroll
        for (int j = 0; j < 4; j++) {
            int col = nt * 128 + wn * 64 + j * 16 + l16;
#pragma unroll
            for (int q = 0; q < 4; q++) {
                int row = mt * 128 + wm * 64 + i * 16 + lk * 4 + q;
                float v = acc[i][j][q];
                if (!SLOT) {
                    v += bias[col];
                    Cb[(size_t)row * N + col] = f2bf(v);
                } else {
                    if (col < NSLOT) Cf[(size_t)row * NSLOT + col] = v + bias[col];
                }
            }
        }
    }
}

// ---------------- attention: one wave per (b,w) word unit ----------------
__global__ __launch_bounds__(256) void attn_kernel(
    const unsigned short* __restrict__ QKV,  // [B*S][2304] bf16: Q|K|V
    const float* __restrict__ res_all,       // [B*S][768] f32
    const int* __restrict__ starts,
    const int* __restrict__ lens,
    unsigned short* __restrict__ word)       // [B*W][768] bf16
{
    int gw = blockIdx.x * 4 + (threadIdx.x >> 6);   // 0..8191
    int lane = threadIdx.x & 63;
    int b = gw >> 8;                                 // W=256
    int s0 = starts[gw];
    int sl = lens[gw];                               // 1..7, wave-uniform
    int h0 = lane * 12;                              // each lane owns 12 h's

    const size_t rowQ = (size_t)(b * SS + s0) * 2304;
    float q[12];
#pragma unroll
    for (int c = 0; c < 3; c++) {
        ushort4 u = *reinterpret_cast<const ushort4*>(&QKV[rowQ + h0 + c * 4]);
        q[c * 4 + 0] = bf2f(u.x); q[c * 4 + 1] = bf2f(u.y);
        q[c * 4 + 2] = bf2f(u.z); q[c * 4 + 3] = bf2f(u.w);
    }

    float scores[8];
#pragma unroll
    for (int k = 0; k < LL; k++) {
        if (k > sl) break;                            // uniform branch
        int s = s0 + k; if (s > SS - 1) s = SS - 1;
        const size_t rowK = (size_t)(b * SS + s) * 2304 + HH;
        float partial = 0.f;
#pragma unroll
        for (int c = 0; c < 3; c++) {
            ushort4 u = *reinterpret_cast<const ushort4*>(&QKV[rowK + h0 + c * 4]);
            partial += q[c * 4 + 0] * bf2f(u.x) + q[c * 4 + 1] * bf2f(u.y)
                     + q[c * 4 + 2] * bf2f(u.z) + q[c * 4 + 3] * bf2f(u.w);
        }
#pragma unroll
        for (int off = 32; off > 0; off >>= 1) partial += __shfl_xor(partial, off);
        scores[k] = partial;
    }

    float m = -1e30f;
    for (int k = 0; k < LL; k++) if (k <= sl && scores[k] > m) m = scores[k];
    float p[8], ssum = 0.f;
    for (int k = 0; k < LL; k++) {
        p[k] = (k <= sl) ? __expf(scores[k] - m) : 0.f;
        ssum += p[k];
    }
    float inv = 1.f / ssum;

    float acc[12];
#pragma unroll
    for (int i = 0; i < 12; i++) acc[i] = 0.f;
    for (int k = 0; k < LL; k++) {
        if (k > sl) break;                            // uniform
        int s = s0 + k; if (s > SS - 1) s = SS - 1;
        const size_t rowV = (size_t)(b * SS + s) * 2304 + 2 * HH;
        float wk = p[k] * inv;
#pragma unroll
        for (int c = 0; c < 3; c++) {
            ushort4 u = *reinterpret_cast<const ushort4*>(&QKV[rowV + h0 + c * 4]);
            acc[c * 4 + 0] += wk * bf2f(u.x); acc[c * 4 + 1] += wk * bf2f(u.y);
            acc[c * 4 + 2] += wk * bf2f(u.z); acc[c * 4 + 3] += wk * bf2f(u.w);
        }
    }

    const float* frow = res_all + (size_t)(b * SS + s0) * HH;
    float fst[12];
#pragma unroll
    for (int c = 0; c < 3; c++) {
        float4 f = *reinterpret_cast<const float4*>(&frow[h0 + c * 4]);
        fst[c * 4 + 0] = f.x; fst[c * 4 + 1] = f.y; fst[c * 4 + 2] = f.z; fst[c * 4 + 3] = f.w;
    }

    unsigned short* wrow = word + (size_t)gw * HH + h0;
#pragma unroll
    for (int c = 0; c < 3; c++) {
        ushort4 o;
        float v0, v1, v2, v3;
        if (sl == 1) { v0 = fst[c*4+0]; v1 = fst[c*4+1]; v2 = fst[c*4+2]; v3 = fst[c*4+3]; }
        else { v0 = acc[c*4+0] + fst[c*4+0]; v1 = acc[c*4+1] + fst[c*4+1];
               v2 = acc[c*4+2] + fst[c*4+2]; v3 = acc[c*4+3] + fst[c*4+3]; }
        o.x = f2bf(v0); o.y = f2bf(v1); o.z = f2bf(v2); o.w = f2bf(v3);
        *reinterpret_cast<ushort4*>(&wrow[c * 4]) = o;
    }
}

// ---------------- res_id: tiny f32 GEMV ----------------
__global__ __launch_bounds__(256) void resid_kernel(
    const float* __restrict__ res, const float* __restrict__ w,
    const float* __restrict__ bias, float* __restrict__ out) {
    int bb = blockIdx.x;
    int t = threadIdx.x, lane = t & 63, wave = t >> 6;
    __shared__ float sres[HH];
    for (int i = t; i < HH; i += 256) sres[i] = res[bb * HH + i];
    __syncthreads();
    for (int o = wave; o < NINTENT; o += 4) {
        float s = 0.f;
        for (int i = lane; i < HH; i += 64) s += sres[i] * w[o * HH + i];
#pragma unroll
        for (int off = 32; off > 0; off >>= 1) s += __shfl_xor(s, off);
        if (lane == 0) out[bb * NINTENT + o] = s + bias[o];
    }
}

// ---------------- launch ----------------
extern "C" void kernel_launch(void* const* d_in, const int* in_sizes, int n_in,
                              void* d_out, int out_size, void* d_ws, size_t ws_size,
                              hipStream_t stream) {
    const float* res_all    = (const float*)d_in[0];
    const float* res        = (const float*)d_in[1];
    const int*   starts     = (const int*)d_in[2];
    const int*   lens       = (const int*)d_in[3];
    const float* Wsq_w      = (const float*)d_in[4];
    const float* Wsq_b      = (const float*)d_in[5];
    const float* Wsk_w      = (const float*)d_in[6];
    const float* Wsk_b      = (const float*)d_in[7];
    const float* Wsv_w      = (const float*)d_in[8];
    const float* Wsv_b      = (const float*)d_in[9];
    const float* lin_id_w   = (const float*)d_in[10];
    const float* lin_id_b   = (const float*)d_in[11];
    const float* lin_slot_w = (const float*)d_in[12];
    const float* lin_slot_b = (const float*)d_in[13];
    float* out = (float*)d_out;

    char* ws = (char*)d_ws;
    // workspace layout (256B aligned, total ~111.6 MiB)
    unsigned short* Abf   = (unsigned short*)(ws + 0);          // 16384x768 bf16
    unsigned short* Wcat  = (unsigned short*)(ws + 25165824);   // 2304x768 bf16
    unsigned short* QKV   = (unsigned short*)(ws + 28704768);   // 16384x2304 bf16
    unsigned short* wordb = (unsigned short*)(ws + 104202240);  // 8192x768 bf16
    unsigned short* slotW = (unsigned short*)(ws + 116785152);  // 128x768 bf16
    float*          biascat = (float*)(ws + 116981760);         // 2304 f32

    cast_f32_bf16<<<4096, 256, 0, stream>>>((const float4*)res_all, (ushort4*)Abf,
                                            (BB * SS * HH) / 4);
    cast_f32_bf16<<<576, 256, 0, stream>>>((const float4*)Wsq_w, (ushort4*)Wcat, (HH * HH) / 4);
    cast_f32_bf16<<<576, 256, 0, stream>>>((const float4*)Wsk_w, (ushort4*)(Wcat + HH * HH), (HH * HH) / 4);
    cast_f32_bf16<<<576, 256, 0, stream>>>((const float4*)Wsv_w, (ushort4*)(Wcat + 2 * HH * HH), (HH * HH) / 4);
    cast_slotw<<<(128 * HH + 255) / 256, 256, 0, stream>>>(lin_slot_w, slotW);
    build_biascat<<<3, 256, 0, stream>>>(Wsq_b, Wsk_b, Wsv_b, biascat);

    // QKV GEMM: M=16384, N=2304 (18 n-tiles)
    gemm128<false><<<128 * 18, 256, 0, stream>>>((const uint4*)Abf, (const uint4*)Wcat,
                                                 biascat, QKV, nullptr, 18, HH);

    // attention: 8192 word units, 1 wave each
    attn_kernel<<<2048, 256, 0, stream>>>(QKV, res_all, starts, lens, wordb);

    // slot GEMM: M=8192, N=128 (121 real cols) -> out[832..]
    gemm128<true><<<64, 256, 0, stream>>>((const uint4*)wordb, (const uint4*)slotW,
                                          lin_slot_b, nullptr, out + 832, 1, HH);

    // res_id
    resid_kernel<<<BB, 256, 0, stream>>>(res, lin_id_w, lin_id_b, out);
}

// Round 2
// 155.287 us; speedup vs baseline: 1.2123x; 1.2123x over previous
//
#include <hip/hip_runtime.h>
#include <cstdint>
#include <cstddef>

// Problem constants
#define BB 32
#define SS 512
#define HH 768
#define WW 256
#define LL 8
#define NINTENT 26
#define NSLOT 121

typedef float f32x4 __attribute__((ext_vector_type(4)));
typedef __bf16 bf16x8 __attribute__((ext_vector_type(8)));

static __device__ __forceinline__ float bf2f(unsigned short u) {
    union { unsigned int i; float f; } x; x.i = ((unsigned int)u) << 16; return x.f;
}
static __device__ __forceinline__ unsigned short f2bf(float f) {
    union { float f; unsigned int i; } x; x.f = f;
    unsigned int r = (x.i + 0x7fffu + ((x.i >> 16) & 1u)) >> 16;
    return (unsigned short)r;
}

// async global->LDS, 16B per lane, wave-uniform LDS base + lane*16
static __device__ __forceinline__ void gload16(const void* g, void* l) {
    __builtin_amdgcn_global_load_lds(
        (const __attribute__((address_space(1))) void*)g,
        (__attribute__((address_space(3))) void*)l, 16, 0, 0);
}

// ---------------- cast kernel (res_all -> bf16) ----------------
__global__ __launch_bounds__(256) void cast_f32_bf16(const float4* __restrict__ src,
                                                     ushort4* __restrict__ dst, int n4) {
    int stride = gridDim.x * blockDim.x;
    for (int i = blockIdx.x * blockDim.x + threadIdx.x; i < n4; i += stride) {
        float4 v = src[i];
        ushort4 o;
        o.x = f2bf(v.x); o.y = f2bf(v.y); o.z = f2bf(v.z); o.w = f2bf(v.w);
        dst[i] = o;
    }
}

// ---------------- fused weight/bias prep ----------------
__global__ __launch_bounds__(256) void prep_kernel(
    const float4* __restrict__ Wq, const float4* __restrict__ Wk,
    const float4* __restrict__ Wv, ushort4* __restrict__ Wcat,
    const float4* __restrict__ slotw, ushort4* __restrict__ slotW,
    const float* __restrict__ bq, const float* __restrict__ bk,
    const float* __restrict__ bv, float* __restrict__ biascat)
{
    const int W4 = (HH * HH) / 4;   // 147456
    int i = blockIdx.x * blockDim.x + threadIdx.x;
    if (i < 3 * W4) {
        float4 v = (i < W4) ? Wq[i] : (i < 2 * W4) ? Wk[i - W4] : Wv[i - 2 * W4];
        ushort4 o;
        o.x = f2bf(v.x); o.y = f2bf(v.y); o.z = f2bf(v.z); o.w = f2bf(v.w);
        Wcat[i] = o;
    } else if (i < 3 * W4 + 128 * HH / 4) {
        int j = i - 3 * W4;            // uint4 index into 128x768
        int r = j / (HH / 4);          // dst row
        ushort4 o = {0, 0, 0, 0};
        if (r < NSLOT) {
            float4 v = slotw[j];
            o.x = f2bf(v.x); o.y = f2bf(v.y); o.z = f2bf(v.z); o.w = f2bf(v.w);
        }
        slotW[j] = o;
    } else if (i < 3 * W4 + 128 * HH / 4 + HH) {
        int j = i - (3 * W4 + 128 * HH / 4);
        biascat[j] = bq[j]; biascat[j + HH] = bk[j]; biascat[j + 2 * HH] = bv[j];
    }
}

// ---------------- QKV GEMM: C[16384][2304] = A[16384][768] * W[2304][768]^T
// m97 structure: 128x128 tile, BK=32, 4 waves (2x2), global_load_lds 16B staging.
__global__ __launch_bounds__(256) void gemm_qkv(
    const uint4* __restrict__ A,    // [16384][96]
    const uint4* __restrict__ Bm,   // [2304][96]
    const float* __restrict__ bias, // [2304]
    unsigned short* __restrict__ C) // [16384][2304] bf16
{
    __shared__ uint4 sA[512];   // 128 rows x 32 bf16 (row-major, 64B rows)
    __shared__ uint4 sB[512];
    const int K8 = 96;
    const int N = 2304;

    // chunked XCD swizzle: 2304 blocks = 8 XCDs x 288
    int bid = blockIdx.x;
    bid = (bid & 7) * 288 + (bid >> 3);
    int mt = bid / 18, nt = bid % 18;

    int t = threadIdx.x;
    int lane = t & 63, wave = t >> 6;
    int wm = wave >> 1, wn = wave & 1;
    int l16 = lane & 15, lk = lane >> 4;

    // staging: wave w stages rows [32w, 32w+32) of both tiles, 2 chunks of 16 rows
    int srow = lane >> 2, schk = lane & 3;
    const uint4* Ag0 = A + (size_t)(mt * 128 + wave * 32 + srow) * K8 + schk;
    const uint4* Ag1 = Ag0 + (size_t)16 * K8;
    const uint4* Bg0 = Bm + (size_t)(nt * 128 + wave * 32 + srow) * K8 + schk;
    const uint4* Bg1 = Bg0 + (size_t)16 * K8;
    uint4* sA0 = &sA[wave * 128];
    uint4* sA1 = &sA[wave * 128 + 64];
    uint4* sB0 = &sB[wave * 128];
    uint4* sB1 = &sB[wave * 128 + 64];

    f32x4 zero = {0.f, 0.f, 0.f, 0.f};
    f32x4 acc[4][4];
#pragma unroll
    for (int i = 0; i < 4; i++)
#pragma unroll
        for (int j = 0; j < 4; j++) acc[i][j] = zero;

    for (int k0 = 0; k0 < K8; k0 += 4) {
        gload16(Ag0 + k0, sA0);
        gload16(Ag1 + k0, sA1);
        gload16(Bg0 + k0, sB0);
        gload16(Bg1 + k0, sB1);
        __syncthreads();

        bf16x8 af[4], bfr[4];
#pragma unroll
        for (int i = 0; i < 4; i++)
            af[i] = *reinterpret_cast<const bf16x8*>(&sA[(wm * 64 + i * 16 + l16) * 4 + lk]);
#pragma unroll
        for (int j = 0; j < 4; j++)
            bfr[j] = *reinterpret_cast<const bf16x8*>(&sB[(wn * 64 + j * 16 + l16) * 4 + lk]);
#pragma unroll
        for (int i = 0; i < 4; i++)
#pragma unroll
            for (int j = 0; j < 4; j++)
                acc[i][j] = __builtin_amdgcn_mfma_f32_16x16x32_bf16(af[i], bfr[j], acc[i][j], 0, 0, 0);
        __syncthreads();
    }

#pragma unroll
    for (int i = 0; i < 4; i++) {
#pragma unroll
        for (int j = 0; j < 4; j++) {
            int col = nt * 128 + wn * 64 + j * 16 + l16;
            float bc = bias[col];
#pragma unroll
            for (int q = 0; q < 4; q++) {
                int row = mt * 128 + wm * 64 + i * 16 + lk * 4 + q;
                C[(size_t)row * N + col] = f2bf(acc[i][j][q] + bc);
            }
        }
    }
}

// ---------------- slot GEMM: out[8192][121] = word[8192][768] * slotW[128][768]^T
// 64x128 tile, 128 blocks, 4 waves (2m x 2n), global_load_lds staging.
__global__ __launch_bounds__(256) void gemm_slot(
    const uint4* __restrict__ A,    // [8192][96]
    const uint4* __restrict__ Bm,   // [128][96]
    const float* __restrict__ bias, // [121]
    float* __restrict__ Cf)         // [8192][121] f32
{
    __shared__ uint4 sA[256];   // 64 rows
    __shared__ uint4 sB[512];   // 128 rows
    const int K8 = 96;

    int mt = blockIdx.x;
    int t = threadIdx.x;
    int lane = t & 63, wave = t >> 6;
    int wm = wave >> 1, wn = wave & 1;
    int l16 = lane & 15, lk = lane >> 4;

    int srow = lane >> 2, schk = lane & 3;
    const uint4* Ag  = A + (size_t)(mt * 64 + wave * 16 + srow) * K8 + schk;
    const uint4* Bg0 = Bm + (size_t)(wave * 32 + srow) * K8 + schk;
    const uint4* Bg1 = Bg0 + (size_t)16 * K8;
    uint4* sAp = &sA[wave * 64];
    uint4* sB0 = &sB[wave * 128];
    uint4* sB1 = &sB[wave * 128 + 64];

    f32x4 zero = {0.f, 0.f, 0.f, 0.f};
    f32x4 acc[2][4];
#pragma unroll
    for (int i = 0; i < 2; i++)
#pragma unroll
        for (int j = 0; j < 4; j++) acc[i][j] = zero;

    for (int k0 = 0; k0 < K8; k0 += 4) {
        gload16(Ag + k0, sAp);
        gload16(Bg0 + k0, sB0);
        gload16(Bg1 + k0, sB1);
        __syncthreads();

        bf16x8 af[2], bfr[4];
#pragma unroll
        for (int i = 0; i < 2; i++)
            af[i] = *reinterpret_cast<const bf16x8*>(&sA[(wm * 32 + i * 16 + l16) * 4 + lk]);
#pragma unroll
        for (int j = 0; j < 4; j++)
            bfr[j] = *reinterpret_cast<const bf16x8*>(&sB[(wn * 64 + j * 16 + l16) * 4 + lk]);
#pragma unroll
        for (int i = 0; i < 2; i++)
#pragma unroll
            for (int j = 0; j < 4; j++)
                acc[i][j] = __builtin_amdgcn_mfma_f32_16x16x32_bf16(af[i], bfr[j], acc[i][j], 0, 0, 0);
        __syncthreads();
    }

#pragma unroll
    for (int i = 0; i < 2; i++) {
#pragma unroll
        for (int j = 0; j < 4; j++) {
            int col = wn * 64 + j * 16 + l16;
            if (col < NSLOT) {
                float bc = bias[col];
#pragma unroll
                for (int q = 0; q < 4; q++) {
                    int row = mt * 64 + wm * 32 + i * 16 + lk * 4 + q;
                    Cf[(size_t)row * NSLOT + col] = acc[i][j][q] + bc;
                }
            }
        }
    }
}

// ---------------- attention: one wave per (b,w) word unit ----------------
__global__ __launch_bounds__(256) void attn_kernel(
    const unsigned short* __restrict__ QKV,  // [B*S][2304] bf16: Q|K|V
    const float* __restrict__ res_all,       // [B*S][768] f32
    const int* __restrict__ starts,
    const int* __restrict__ lens,
    unsigned short* __restrict__ word)       // [B*W][768] bf16
{
    // chunked XCD swizzle: 2048 blocks = 8 x 256 -> one batch's blocks stay on one XCD
    int bid = blockIdx.x;
    bid = (bid & 7) * 256 + (bid >> 3);
    int gw = bid * 4 + (threadIdx.x >> 6);           // 0..8191
    int lane = threadIdx.x & 63;
    int b = gw >> 8;                                 // W=256
    int s0 = starts[gw];
    int sl = lens[gw];                               // 1..7, wave-uniform
    int h0 = lane * 12;                              // each lane owns 12 h's

    const size_t rowQ = (size_t)(b * SS + s0) * 2304;
    float q[12];
#pragma unroll
    for (int c = 0; c < 3; c++) {
        ushort4 u = *reinterpret_cast<const ushort4*>(&QKV[rowQ + h0 + c * 4]);
        q[c * 4 + 0] = bf2f(u.x); q[c * 4 + 1] = bf2f(u.y);
        q[c * 4 + 2] = bf2f(u.z); q[c * 4 + 3] = bf2f(u.w);
    }

    float scores[8];
#pragma unroll
    for (int k = 0; k < LL; k++) {
        if (k > sl) break;                            // uniform branch
        int s = s0 + k; if (s > SS - 1) s = SS - 1;
        const size_t rowK = (size_t)(b * SS + s) * 2304 + HH;
        float partial = 0.f;
#pragma unroll
        for (int c = 0; c < 3; c++) {
            ushort4 u = *reinterpret_cast<const ushort4*>(&QKV[rowK + h0 + c * 4]);
            partial += q[c * 4 + 0] * bf2f(u.x) + q[c * 4 + 1] * bf2f(u.y)
                     + q[c * 4 + 2] * bf2f(u.z) + q[c * 4 + 3] * bf2f(u.w);
        }
#pragma unroll
        for (int off = 32; off > 0; off >>= 1) partial += __shfl_xor(partial, off);
        scores[k] = partial;
    }

    float m = -1e30f;
    for (int k = 0; k < LL; k++) if (k <= sl && scores[k] > m) m = scores[k];
    float p[8], ssum = 0.f;
    for (int k = 0; k < LL; k++) {
        p[k] = (k <= sl) ? __expf(scores[k] - m) : 0.f;
        ssum += p[k];
    }
    float inv = 1.f / ssum;

    float acc[12];
#pragma unroll
    for (int i = 0; i < 12; i++) acc[i] = 0.f;
    for (int k = 0; k < LL; k++) {
        if (k > sl) break;                            // uniform
        int s = s0 + k; if (s > SS - 1) s = SS - 1;
        const size_t rowV = (size_t)(b * SS + s) * 2304 + 2 * HH;
        float wk = p[k] * inv;
#pragma unroll
        for (int c = 0; c < 3; c++) {
            ushort4 u = *reinterpret_cast<const ushort4*>(&QKV[rowV + h0 + c * 4]);
            acc[c * 4 + 0] += wk * bf2f(u.x); acc[c * 4 + 1] += wk * bf2f(u.y);
            acc[c * 4 + 2] += wk * bf2f(u.z); acc[c * 4 + 3] += wk * bf2f(u.w);
        }
    }

    const float* frow = res_all + (size_t)(b * SS + s0) * HH;
    float fst[12];
#pragma unroll
    for (int c = 0; c < 3; c++) {
        float4 f = *reinterpret_cast<const float4*>(&frow[h0 + c * 4]);
        fst[c * 4 + 0] = f.x; fst[c * 4 + 1] = f.y; fst[c * 4 + 2] = f.z; fst[c * 4 + 3] = f.w;
    }

    unsigned short* wrow = word + (size_t)gw * HH + h0;
#pragma unroll
    for (int c = 0; c < 3; c++) {
        ushort4 o;
        float v0, v1, v2, v3;
        if (sl == 1) { v0 = fst[c*4+0]; v1 = fst[c*4+1]; v2 = fst[c*4+2]; v3 = fst[c*4+3]; }
        else { v0 = acc[c*4+0] + fst[c*4+0]; v1 = acc[c*4+1] + fst[c*4+1];
               v2 = acc[c*4+2] + fst[c*4+2]; v3 = acc[c*4+3] + fst[c*4+3]; }
        o.x = f2bf(v0); o.y = f2bf(v1); o.z = f2bf(v2); o.w = f2bf(v3);
        *reinterpret_cast<ushort4*>(&wrow[c * 4]) = o;
    }
}

// ---------------- res_id: tiny f32 GEMV ----------------
__global__ __launch_bounds__(256) void resid_kernel(
    const float* __restrict__ res, const float* __restrict__ w,
    const float* __restrict__ bias, float* __restrict__ out) {
    int bb = blockIdx.x;
    int t = threadIdx.x, lane = t & 63, wave = t >> 6;
    __shared__ float sres[HH];
    for (int i = t; i < HH; i += 256) sres[i] = res[bb * HH + i];
    __syncthreads();
    for (int o = wave; o < NINTENT; o += 4) {
        float s = 0.f;
        for (int i = lane; i < HH; i += 64) s += sres[i] * w[o * HH + i];
#pragma unroll
        for (int off = 32; off > 0; off >>= 1) s += __shfl_xor(s, off);
        if (lane == 0) out[bb * NINTENT + o] = s + bias[o];
    }
}

// ---------------- launch ----------------
extern "C" void kernel_launch(void* const* d_in, const int* in_sizes, int n_in,
                              void* d_out, int out_size, void* d_ws, size_t ws_size,
                              hipStream_t stream) {
    const float* res_all    = (const float*)d_in[0];
    const float* res        = (const float*)d_in[1];
    const int*   starts     = (const int*)d_in[2];
    const int*   lens       = (const int*)d_in[3];
    const float* Wsq_w      = (const float*)d_in[4];
    const float* Wsq_b      = (const float*)d_in[5];
    const float* Wsk_w      = (const float*)d_in[6];
    const float* Wsk_b      = (const float*)d_in[7];
    const float* Wsv_w      = (const float*)d_in[8];
    const float* Wsv_b      = (const float*)d_in[9];
    const float* lin_id_w   = (const float*)d_in[10];
    const float* lin_id_b   = (const float*)d_in[11];
    const float* lin_slot_w = (const float*)d_in[12];
    const float* lin_slot_b = (const float*)d_in[13];
    float* out = (float*)d_out;

    char* ws = (char*)d_ws;
    // workspace layout (16B aligned, total ~111.6 MiB)
    unsigned short* Abf   = (unsigned short*)(ws + 0);          // 16384x768 bf16
    unsigned short* Wcat  = (unsigned short*)(ws + 25165824);   // 2304x768 bf16
    unsigned short* QKV   = (unsigned short*)(ws + 28704768);   // 16384x2304 bf16
    unsigned short* wordb = (unsigned short*)(ws + 104202240);  // 8192x768 bf16
    unsigned short* slotW = (unsigned short*)(ws + 116785152);  // 128x768 bf16
    float*          biascat = (float*)(ws + 116981760);         // 2304 f32

    cast_f32_bf16<<<4096, 256, 0, stream>>>((const float4*)res_all, (ushort4*)Abf,
                                            (BB * SS * HH) / 4);

    prep_kernel<<<1827, 256, 0, stream>>>(
        (const float4*)Wsq_w, (const float4*)Wsk_w, (const float4*)Wsv_w,
        (ushort4*)Wcat, (const float4*)lin_slot_w, (ushort4*)slotW,
        Wsq_b, Wsk_b, Wsv_b, biascat);

    // QKV GEMM: M=16384, N=2304 (18 n-tiles x 128 m-tiles = 2304 blocks)
    gemm_qkv<<<2304, 256, 0, stream>>>((const uint4*)Abf, (const uint4*)Wcat,
                                       biascat, QKV);

    // attention: 8192 word units, 1 wave each
    attn_kernel<<<2048, 256, 0, stream>>>(QKV, res_all, starts, lens, wordb);

    // slot GEMM: M=8192 (128 tiles of 64), N=128 (121 real cols)
    gemm_slot<<<128, 256, 0, stream>>>((const uint4*)wordb, (const uint4*)slotW,
                                       lin_slot_b, out + 832);

    // res_id
    resid_kernel<<<BB, 256, 0, stream>>>(res, lin_id_w, lin_id_b, out);
}

// Round 3
// 154.894 us; speedup vs baseline: 1.2154x; 1.0025x over previous
//
#include <hip/hip_runtime.h>
#include <cstdint>
#include <cstddef>

// Problem constants
#define BB 32
#define SS 512
#define HH 768
#define WW 256
#define LL 8
#define NINTENT 26
#define NSLOT 121

typedef float f32x4 __attribute__((ext_vector_type(4)));
typedef __bf16 bf16x8 __attribute__((ext_vector_type(8)));

static __device__ __forceinline__ float bf2f(unsigned short u) {
    union { unsigned int i; float f; } x; x.i = ((unsigned int)u) << 16; return x.f;
}
static __device__ __forceinline__ unsigned short f2bf(float f) {
    union { float f; unsigned int i; } x; x.f = f;
    unsigned int r = (x.i + 0x7fffu + ((x.i >> 16) & 1u)) >> 16;
    return (unsigned short)r;
}

// async global->LDS, 16B per lane, wave-uniform LDS base + lane*16
static __device__ __forceinline__ void gload16(const void* g, void* l) {
    __builtin_amdgcn_global_load_lds(
        (const __attribute__((address_space(1))) void*)g,
        (__attribute__((address_space(3))) void*)l, 16, 0, 0);
}

#define MF(a, b, c) __builtin_amdgcn_mfma_f32_16x16x32_bf16((a), (b), (c), 0, 0, 0)

// ---------------- cast kernel (res_all -> bf16) ----------------
__global__ __launch_bounds__(256) void cast_f32_bf16(const float4* __restrict__ src,
                                                     ushort4* __restrict__ dst, int n4) {
    int stride = gridDim.x * blockDim.x;
    for (int i = blockIdx.x * blockDim.x + threadIdx.x; i < n4; i += stride) {
        float4 v = src[i];
        ushort4 o;
        o.x = f2bf(v.x); o.y = f2bf(v.y); o.z = f2bf(v.z); o.w = f2bf(v.w);
        dst[i] = o;
    }
}

// ---------------- fused weight/bias prep ----------------
__global__ __launch_bounds__(256) void prep_kernel(
    const float4* __restrict__ Wq, const float4* __restrict__ Wk,
    const float4* __restrict__ Wv, ushort4* __restrict__ Wcat,
    const float4* __restrict__ slotw, ushort4* __restrict__ slotW,
    const float* __restrict__ bq, const float* __restrict__ bk,
    const float* __restrict__ bv, float* __restrict__ biascat)
{
    const int W4 = (HH * HH) / 4;   // 147456
    int i = blockIdx.x * blockDim.x + threadIdx.x;
    if (i < 3 * W4) {
        float4 v = (i < W4) ? Wq[i] : (i < 2 * W4) ? Wk[i - W4] : Wv[i - 2 * W4];
        ushort4 o;
        o.x = f2bf(v.x); o.y = f2bf(v.y); o.z = f2bf(v.z); o.w = f2bf(v.w);
        Wcat[i] = o;
    } else if (i < 3 * W4 + 128 * HH / 4) {
        int j = i - 3 * W4;            // uint4 index into 128x768
        int r = j / (HH / 4);          // dst row
        ushort4 o = {0, 0, 0, 0};
        if (r < NSLOT) {
            float4 v = slotw[j];
            o.x = f2bf(v.x); o.y = f2bf(v.y); o.z = f2bf(v.z); o.w = f2bf(v.w);
        }
        slotW[j] = o;
    } else if (i < 3 * W4 + 128 * HH / 4 + HH) {
        int j = i - (3 * W4 + 128 * HH / 4);
        biascat[j] = bq[j]; biascat[j + HH] = bk[j]; biascat[j + 2 * HH] = bv[j];
    }
}

// ---------------- QKV GEMM v2: C[16384][2304] = A[16384][768] * W[2304][768]^T
// 256x256 tile, BK=32, 8 waves (2M x 4N), 3-buffer LDS rotation (96 KiB),
// 2-tile global_load_lds prefetch, counted vmcnt(4), 1 barrier per K-tile,
// setprio around MFMA clusters.
__global__ __launch_bounds__(512, 2) void gemm_qkv2(
    const uint4* __restrict__ A,    // [16384][96]
    const uint4* __restrict__ Bm,   // [2304][96]
    const float* __restrict__ bias, // [2304]
    unsigned short* __restrict__ C) // [16384][2304] bf16
{
    extern __shared__ char smem[];  // 3 x (A 16KB + B 16KB) = 98304 B
    const int K8 = 96;
    const int N = 2304;

    // chunked XCD swizzle: 576 blocks = 8 XCDs x 72
    int bid = blockIdx.x;
    bid = (bid & 7) * 72 + (bid >> 3);
    const int mt = bid / 9, nt = bid % 9;

    const int tt = threadIdx.x;
    const int lane = tt & 63, wave = tt >> 6;
    const int wm = wave >> 2, wn = wave & 3;     // 2 x 4 wave grid
    const int l16 = lane & 15, lk = lane >> 4;

    // staging source (per thread): row tt>>2 (0..127) and +128, chunk tt&3
    const uint4* Asrc = A + (size_t)(mt * 256 + (tt >> 2)) * K8 + (tt & 3);
    const uint4* Bsrc = Bm + (size_t)(nt * 256 + (tt >> 2)) * K8 + (tt & 3);
    // LDS stage bases (wave-uniform; HW adds lane*16)
    char* ldsA = smem + wave * 1024;
    char* ldsB = smem + 16384 + wave * 1024;
    // LDS frag-read base offsets
    const int aOff = (wm * 128 + l16) * 64 + lk * 16;
    const int bOff = 16384 + (wn * 64 + l16) * 64 + lk * 16;

    f32x4 acc[8][4] = {};

#define STAGE_A(T, D) { gload16(Asrc + (T) * 4,         ldsA + (D) * 32768); \
                        gload16(Asrc + (T) * 4 + 12288, ldsA + (D) * 32768 + 8192); }
#define STAGE_B(T, D) { gload16(Bsrc + (T) * 4,         ldsB + (D) * 32768); \
                        gload16(Bsrc + (T) * 4 + 12288, ldsB + (D) * 32768 + 8192); }

#define TILE(D, TSTAGE, DSTAGE, DO_STAGE, WAITN, DO_BAR) do {                    \
    const char* ab_ = smem + (D) * 32768 + aOff;                                 \
    const char* bb_ = smem + (D) * 32768 + bOff;                                 \
    bf16x8 af_[4], bf_[4];                                                       \
    _Pragma("unroll") for (int i_ = 0; i_ < 4; i_++)                             \
        af_[i_] = *(const bf16x8*)(ab_ + i_ * 1024);                             \
    _Pragma("unroll") for (int j_ = 0; j_ < 4; j_++)                             \
        bf_[j_] = *(const bf16x8*)(bb_ + j_ * 1024);                             \
    if (DO_STAGE) { STAGE_A(TSTAGE, DSTAGE); }                                   \
    __builtin_amdgcn_s_setprio(1);                                               \
    _Pragma("unroll") for (int i_ = 0; i_ < 4; i_++)                             \
        _Pragma("unroll") for (int j_ = 0; j_ < 4; j_++)                         \
            acc[i_][j_] = MF(af_[i_], bf_[j_], acc[i_][j_]);                     \
    __builtin_amdgcn_s_setprio(0);                                               \
    _Pragma("unroll") for (int i_ = 0; i_ < 4; i_++)                             \
        af_[i_] = *(const bf16x8*)(ab_ + 4096 + i_ * 1024);                      \
    if (DO_STAGE) { STAGE_B(TSTAGE, DSTAGE); }                                   \
    __builtin_amdgcn_s_setprio(1);                                               \
    _Pragma("unroll") for (int i_ = 0; i_ < 4; i_++)                             \
        _Pragma("unroll") for (int j_ = 0; j_ < 4; j_++)                         \
            acc[4 + i_][j_] = MF(af_[i_], bf_[j_], acc[4 + i_][j_]);             \
    __builtin_amdgcn_s_setprio(0);                                               \
    if ((WAITN) == 4)      asm volatile("s_waitcnt vmcnt(4)" ::: "memory");      \
    else if ((WAITN) == 0) asm volatile("s_waitcnt vmcnt(0)" ::: "memory");      \
    if (DO_BAR) { __builtin_amdgcn_s_barrier();                                  \
                  __builtin_amdgcn_sched_barrier(0); }                           \
} while (0)

    // prologue: stage tiles 0,1; wait for tile 0; barrier
    STAGE_A(0, 0); STAGE_B(0, 0);
    STAGE_A(1, 1); STAGE_B(1, 1);
    asm volatile("s_waitcnt vmcnt(4)" ::: "memory");
    __builtin_amdgcn_s_barrier();
    __builtin_amdgcn_sched_barrier(0);

    // main: tiles 0..20 (7 groups of 3), each stages t+2, vmcnt(4), barrier
    for (int t0 = 0; t0 < 21; t0 += 3) {
        TILE(0, t0 + 2, 2, true, 4, true);
        TILE(1, t0 + 3, 0, true, 4, true);
        TILE(2, t0 + 4, 1, true, 4, true);
    }
    // tail: t=21 (stages 23), t=22 (drain to 0), t=23 (no barrier)
    TILE(0, 23, 2, true, 4, true);
    TILE(1, 0, 0, false, 0, true);
    TILE(2, 0, 0, false, -1, false);

#undef TILE
#undef STAGE_A
#undef STAGE_B

    // epilogue: bias + bf16 store
#pragma unroll
    for (int fm = 0; fm < 8; fm++) {
#pragma unroll
        for (int j = 0; j < 4; j++) {
            int col = nt * 256 + wn * 64 + j * 16 + l16;
            float bc = bias[col];
#pragma unroll
            for (int q = 0; q < 4; q++) {
                int row = mt * 256 + wm * 128 + fm * 16 + lk * 4 + q;
                C[(size_t)row * N + col] = f2bf(acc[fm][j][q] + bc);
            }
        }
    }
}

// ---------------- slot GEMM: out[8192][121] = word[8192][768] * slotW[128][768]^T
__global__ __launch_bounds__(256) void gemm_slot(
    const uint4* __restrict__ A,    // [8192][96]
    const uint4* __restrict__ Bm,   // [128][96]
    const float* __restrict__ bias, // [121]
    float* __restrict__ Cf)         // [8192][121] f32
{
    __shared__ uint4 sA[256];   // 64 rows
    __shared__ uint4 sB[512];   // 128 rows
    const int K8 = 96;

    int mt = blockIdx.x;
    int t = threadIdx.x;
    int lane = t & 63, wave = t >> 6;
    int wm = wave >> 1, wn = wave & 1;
    int l16 = lane & 15, lk = lane >> 4;

    int srow = lane >> 2, schk = lane & 3;
    const uint4* Ag  = A + (size_t)(mt * 64 + wave * 16 + srow) * K8 + schk;
    const uint4* Bg0 = Bm + (size_t)(wave * 32 + srow) * K8 + schk;
    const uint4* Bg1 = Bg0 + (size_t)16 * K8;
    uint4* sAp = &sA[wave * 64];
    uint4* sB0 = &sB[wave * 128];
    uint4* sB1 = &sB[wave * 128 + 64];

    f32x4 zero = {0.f, 0.f, 0.f, 0.f};
    f32x4 acc[2][4];
#pragma unroll
    for (int i = 0; i < 2; i++)
#pragma unroll
        for (int j = 0; j < 4; j++) acc[i][j] = zero;

    for (int k0 = 0; k0 < K8; k0 += 4) {
        gload16(Ag + k0, sAp);
        gload16(Bg0 + k0, sB0);
        gload16(Bg1 + k0, sB1);
        __syncthreads();

        bf16x8 af[2], bfr[4];
#pragma unroll
        for (int i = 0; i < 2; i++)
            af[i] = *reinterpret_cast<const bf16x8*>(&sA[(wm * 32 + i * 16 + l16) * 4 + lk]);
#pragma unroll
        for (int j = 0; j < 4; j++)
            bfr[j] = *reinterpret_cast<const bf16x8*>(&sB[(wn * 64 + j * 16 + l16) * 4 + lk]);
#pragma unroll
        for (int i = 0; i < 2; i++)
#pragma unroll
            for (int j = 0; j < 4; j++)
                acc[i][j] = MF(af[i], bfr[j], acc[i][j]);
        __syncthreads();
    }

#pragma unroll
    for (int i = 0; i < 2; i++) {
#pragma unroll
        for (int j = 0; j < 4; j++) {
            int col = wn * 64 + j * 16 + l16;
            if (col < NSLOT) {
                float bc = bias[col];
#pragma unroll
                for (int q = 0; q < 4; q++) {
                    int row = mt * 64 + wm * 32 + i * 16 + lk * 4 + q;
                    Cf[(size_t)row * NSLOT + col] = acc[i][j][q] + bc;
                }
            }
        }
    }
}

// ---------------- attention: one wave per (b,w) word unit ----------------
__global__ __launch_bounds__(256) void attn_kernel(
    const unsigned short* __restrict__ QKV,  // [B*S][2304] bf16: Q|K|V
    const float* __restrict__ res_all,       // [B*S][768] f32
    const int* __restrict__ starts,
    const int* __restrict__ lens,
    unsigned short* __restrict__ word)       // [B*W][768] bf16
{
    // chunked XCD swizzle: 2048 blocks = 8 x 256 -> one batch's blocks stay on one XCD
    int bid = blockIdx.x;
    bid = (bid & 7) * 256 + (bid >> 3);
    int gw = bid * 4 + (threadIdx.x >> 6);           // 0..8191
    int lane = threadIdx.x & 63;
    int b = gw >> 8;                                 // W=256
    int s0 = starts[gw];
    int sl = lens[gw];                               // 1..7, wave-uniform
    int h0 = lane * 12;                              // each lane owns 12 h's

    const size_t rowQ = (size_t)(b * SS + s0) * 2304;
    float q[12];
#pragma unroll
    for (int c = 0; c < 3; c++) {
        ushort4 u = *reinterpret_cast<const ushort4*>(&QKV[rowQ + h0 + c * 4]);
        q[c * 4 + 0] = bf2f(u.x); q[c * 4 + 1] = bf2f(u.y);
        q[c * 4 + 2] = bf2f(u.z); q[c * 4 + 3] = bf2f(u.w);
    }

    float scores[8];
#pragma unroll
    for (int k = 0; k < LL; k++) {
        if (k > sl) break;                            // uniform branch
        int s = s0 + k; if (s > SS - 1) s = SS - 1;
        const size_t rowK = (size_t)(b * SS + s) * 2304 + HH;
        float partial = 0.f;
#pragma unroll
        for (int c = 0; c < 3; c++) {
            ushort4 u = *reinterpret_cast<const ushort4*>(&QKV[rowK + h0 + c * 4]);
            partial += q[c * 4 + 0] * bf2f(u.x) + q[c * 4 + 1] * bf2f(u.y)
                     + q[c * 4 + 2] * bf2f(u.z) + q[c * 4 + 3] * bf2f(u.w);
        }
#pragma unroll
        for (int off = 32; off > 0; off >>= 1) partial += __shfl_xor(partial, off);
        scores[k] = partial;
    }

    float m = -1e30f;
    for (int k = 0; k < LL; k++) if (k <= sl && scores[k] > m) m = scores[k];
    float p[8], ssum = 0.f;
    for (int k = 0; k < LL; k++) {
        p[k] = (k <= sl) ? __expf(scores[k] - m) : 0.f;
        ssum += p[k];
    }
    float inv = 1.f / ssum;

    float acc[12];
#pragma unroll
    for (int i = 0; i < 12; i++) acc[i] = 0.f;
    for (int k = 0; k < LL; k++) {
        if (k > sl) break;                            // uniform
        int s = s0 + k; if (s > SS - 1) s = SS - 1;
        const size_t rowV = (size_t)(b * SS + s) * 2304 + 2 * HH;
        float wk = p[k] * inv;
#pragma unroll
        for (int c = 0; c < 3; c++) {
            ushort4 u = *reinterpret_cast<const ushort4*>(&QKV[rowV + h0 + c * 4]);
            acc[c * 4 + 0] += wk * bf2f(u.x); acc[c * 4 + 1] += wk * bf2f(u.y);
            acc[c * 4 + 2] += wk * bf2f(u.z); acc[c * 4 + 3] += wk * bf2f(u.w);
        }
    }

    const float* frow = res_all + (size_t)(b * SS + s0) * HH;
    float fst[12];
#pragma unroll
    for (int c = 0; c < 3; c++) {
        float4 f = *reinterpret_cast<const float4*>(&frow[h0 + c * 4]);
        fst[c * 4 + 0] = f.x; fst[c * 4 + 1] = f.y; fst[c * 4 + 2] = f.z; fst[c * 4 + 3] = f.w;
    }

    unsigned short* wrow = word + (size_t)gw * HH + h0;
#pragma unroll
    for (int c = 0; c < 3; c++) {
        ushort4 o;
        float v0, v1, v2, v3;
        if (sl == 1) { v0 = fst[c*4+0]; v1 = fst[c*4+1]; v2 = fst[c*4+2]; v3 = fst[c*4+3]; }
        else { v0 = acc[c*4+0] + fst[c*4+0]; v1 = acc[c*4+1] + fst[c*4+1];
               v2 = acc[c*4+2] + fst[c*4+2]; v3 = acc[c*4+3] + fst[c*4+3]; }
        o.x = f2bf(v0); o.y = f2bf(v1); o.z = f2bf(v2); o.w = f2bf(v3);
        *reinterpret_cast<ushort4*>(&wrow[c * 4]) = o;
    }
}

// ---------------- res_id: tiny f32 GEMV ----------------
__global__ __launch_bounds__(256) void resid_kernel(
    const float* __restrict__ res, const float* __restrict__ w,
    const float* __restrict__ bias, float* __restrict__ out) {
    int bb = blockIdx.x;
    int t = threadIdx.x, lane = t & 63, wave = t >> 6;
    __shared__ float sres[HH];
    for (int i = t; i < HH; i += 256) sres[i] = res[bb * HH + i];
    __syncthreads();
    for (int o = wave; o < NINTENT; o += 4) {
        float s = 0.f;
        for (int i = lane; i < HH; i += 64) s += sres[i] * w[o * HH + i];
#pragma unroll
        for (int off = 32; off > 0; off >>= 1) s += __shfl_xor(s, off);
        if (lane == 0) out[bb * NINTENT + o] = s + bias[o];
    }
}

// ---------------- launch ----------------
extern "C" void kernel_launch(void* const* d_in, const int* in_sizes, int n_in,
                              void* d_out, int out_size, void* d_ws, size_t ws_size,
                              hipStream_t stream) {
    const float* res_all    = (const float*)d_in[0];
    const float* res        = (const float*)d_in[1];
    const int*   starts     = (const int*)d_in[2];
    const int*   lens       = (const int*)d_in[3];
    const float* Wsq_w      = (const float*)d_in[4];
    const float* Wsq_b      = (const float*)d_in[5];
    const float* Wsk_w      = (const float*)d_in[6];
    const float* Wsk_b      = (const float*)d_in[7];
    const float* Wsv_w      = (const float*)d_in[8];
    const float* Wsv_b      = (const float*)d_in[9];
    const float* lin_id_w   = (const float*)d_in[10];
    const float* lin_id_b   = (const float*)d_in[11];
    const float* lin_slot_w = (const float*)d_in[12];
    const float* lin_slot_b = (const float*)d_in[13];
    float* out = (float*)d_out;

    char* ws = (char*)d_ws;
    unsigned short* Abf   = (unsigned short*)(ws + 0);          // 16384x768 bf16
    unsigned short* Wcat  = (unsigned short*)(ws + 25165824);   // 2304x768 bf16
    unsigned short* QKV   = (unsigned short*)(ws + 28704768);   // 16384x2304 bf16
    unsigned short* wordb = (unsigned short*)(ws + 104202240);  // 8192x768 bf16
    unsigned short* slotW = (unsigned short*)(ws + 116785152);  // 128x768 bf16
    float*          biascat = (float*)(ws + 116981760);         // 2304 f32

    // allow 96 KiB dynamic LDS for gemm_qkv2 (idempotent, host-side, capture-safe)
    hipFuncSetAttribute((const void*)gemm_qkv2,
                        hipFuncAttributeMaxDynamicSharedMemorySize, 98304);

    cast_f32_bf16<<<4096, 256, 0, stream>>>((const float4*)res_all, (ushort4*)Abf,
                                            (BB * SS * HH) / 4);

    prep_kernel<<<1827, 256, 0, stream>>>(
        (const float4*)Wsq_w, (const float4*)Wsk_w, (const float4*)Wsv_w,
        (ushort4*)Wcat, (const float4*)lin_slot_w, (ushort4*)slotW,
        Wsq_b, Wsk_b, Wsv_b, biascat);

    // QKV GEMM: M=16384 (64 m-tiles), N=2304 (9 n-tiles) -> 576 blocks
    gemm_qkv2<<<576, 512, 98304, stream>>>((const uint4*)Abf, (const uint4*)Wcat,
                                           biascat, QKV);

    // attention: 8192 word units, 1 wave each
    attn_kernel<<<2048, 256, 0, stream>>>(QKV, res_all, starts, lens, wordb);

    // slot GEMM: M=8192 (128 tiles of 64), N=128 (121 real cols)
    gemm_slot<<<128, 256, 0, stream>>>((const uint4*)wordb, (const uint4*)slotW,
                                       lin_slot_b, out + 832);

    // res_id
    resid_kernel<<<BB, 256, 0, stream>>>(res, lin_id_w, lin_id_b, out);
}

// Round 4
// 151.315 us; speedup vs baseline: 1.2442x; 1.0237x over previous
//
#include <hip/hip_runtime.h>
#include <cstdint>
#include <cstddef>

// Problem constants
#define BB 32
#define SS 512
#define HH 768
#define WW 256
#define LL 8
#define NINTENT 26
#define NSLOT 121

typedef float f32x4 __attribute__((ext_vector_type(4)));
typedef __bf16 bf16x8 __attribute__((ext_vector_type(8)));

static __device__ __forceinline__ float bf2f(unsigned short u) {
    union { unsigned int i; float f; } x; x.i = ((unsigned int)u) << 16; return x.f;
}
static __device__ __forceinline__ unsigned short f2bf(float f) {
    union { float f; unsigned int i; } x; x.f = f;
    unsigned int r = (x.i + 0x7fffu + ((x.i >> 16) & 1u)) >> 16;
    return (unsigned short)r;
}

// async global->LDS, 16B per lane, wave-uniform LDS base + lane*16
static __device__ __forceinline__ void gload16(const void* g, void* l) {
    __builtin_amdgcn_global_load_lds(
        (const __attribute__((address_space(1))) void*)g,
        (__attribute__((address_space(3))) void*)l, 16, 0, 0);
}

#define MF(a, b, c) __builtin_amdgcn_mfma_f32_16x16x32_bf16((a), (b), (c), 0, 0, 0)

// ---------------- cast kernel (res_all -> bf16) ----------------
__global__ __launch_bounds__(256) void cast_f32_bf16(const float4* __restrict__ src,
                                                     ushort4* __restrict__ dst, int n4) {
    int stride = gridDim.x * blockDim.x;
    for (int i = blockIdx.x * blockDim.x + threadIdx.x; i < n4; i += stride) {
        float4 v = src[i];
        ushort4 o;
        o.x = f2bf(v.x); o.y = f2bf(v.y); o.z = f2bf(v.z); o.w = f2bf(v.w);
        dst[i] = o;
    }
}

// ---------------- fused weight/bias prep ----------------
__global__ __launch_bounds__(256) void prep_kernel(
    const float4* __restrict__ Wq, const float4* __restrict__ Wk,
    const float4* __restrict__ Wv, ushort4* __restrict__ Wcat,
    const float4* __restrict__ slotw, ushort4* __restrict__ slotW,
    const float* __restrict__ bq, const float* __restrict__ bk,
    const float* __restrict__ bv, float* __restrict__ biascat)
{
    const int W4 = (HH * HH) / 4;   // 147456
    int i = blockIdx.x * blockDim.x + threadIdx.x;
    if (i < 3 * W4) {
        float4 v = (i < W4) ? Wq[i] : (i < 2 * W4) ? Wk[i - W4] : Wv[i - 2 * W4];
        ushort4 o;
        o.x = f2bf(v.x); o.y = f2bf(v.y); o.z = f2bf(v.z); o.w = f2bf(v.w);
        Wcat[i] = o;
    } else if (i < 3 * W4 + 128 * HH / 4) {
        int j = i - 3 * W4;            // uint4 index into 128x768
        int r = j / (HH / 4);          // dst row
        ushort4 o = {0, 0, 0, 0};
        if (r < NSLOT) {
            float4 v = slotw[j];
            o.x = f2bf(v.x); o.y = f2bf(v.y); o.z = f2bf(v.z); o.w = f2bf(v.w);
        }
        slotW[j] = o;
    } else if (i < 3 * W4 + 128 * HH / 4 + HH) {
        int j = i - (3 * W4 + 128 * HH / 4);
        biascat[j] = bq[j]; biascat[j + HH] = bk[j]; biascat[j + 2 * HH] = bv[j];
    }
}

// ---------------- QKV GEMM v3: 8-phase 256x256 template (m201 port) --------
// C[16384][2304] = A[16384][768] * W[2304][768]^T, BK=64, 12 K-tiles.
// 8 waves (2M x 4N), LDS 128 KiB = 2 bufs x {A: 2x16KB halves, B: 2x16KB halves}.
// Per K-tile: 4 phases, each = {ds_reads | 1 half-tile stage | barrier |
// lgkmcnt(0) | 16 MFMA setprio-wrapped | barrier}. Counted vmcnt(4) once per
// K-tile. LDS swizzle: 16B-chunk ^= (row&7), applied via pre-swizzled global
// source (linear gload_lds dest) + XOR on ds_read address (involution).
//
// Race-freedom (phase-lockstep via barriers):
//   B(u) fully read at phase (u,0)  -> B region of buf u&1 free from (u,1)
//   A(u) fully read at phase (u,3)  -> A region of buf u&1 free from (u+1,0)
// Stage schedule: (u,0):A0(u+1) (u,1):A1(u+1) [buf ~u, A(u-1) retired ✓]
//                 (u,2):B0(u+2) (u,3):B1(u+2) [buf u, B(u) retired ✓]
// Boundary vmcnt(4) at end of (u,3) retires A(u+1) (leaves B(u+2) in flight),
// then barrier -> all waves' stages for tile u+1 landed before any (u+1,0) read.
__global__ __launch_bounds__(512, 2) void gemm_qkv3(
    const uint4* __restrict__ A,    // [16384][96]
    const uint4* __restrict__ Bm,   // [2304][96]
    const float* __restrict__ bias, // [2304]
    unsigned short* __restrict__ C) // [16384][2304] bf16
{
    extern __shared__ char smem[];  // 131072 B
    const int N = 2304;

    // chunked XCD swizzle: 576 blocks = 8 XCDs x 72
    int bid = blockIdx.x;
    bid = (bid & 7) * 72 + (bid >> 3);
    const int mt = bid / 9, nt = bid % 9;

    const int t = threadIdx.x;
    const int lane = t & 63, wave = t >> 6;
    const int wm = wave >> 2, wn = wave & 3;     // 2 x 4 wave grid
    const int l16 = lane & 15, lk = lane >> 4;

    // ---- staging source (pre-swizzled): thread t covers rows r0, r0+64 ----
    const int r0 = t >> 3;                       // 0..63
    const int cgx = (t & 7) ^ (r0 & 7);          // swizzled 16B chunk
    const uint4* pA0 = A  + (size_t)(mt * 256 + r0) * 96 + cgx;        // A rows 0-127
    const uint4* pA1 = pA0 + (size_t)128 * 96;                         // A rows 128-255
    const uint4* pB0 = Bm + (size_t)(nt * 256 + r0) * 96 + cgx;        // B rows 0-127
    const uint4* pB1 = pB0 + (size_t)128 * 96;                         // B rows 128-255
    char* ldsStage = smem + wave * 1024;         // + HW lane*16

    // ---- ds_read bases (swizzled chunk per kk) ----
    const int aBase = wm * 16384 + l16 * 128;
    const int bBase = 32768 + (wn >> 1) * 16384 + ((wn & 1) * 64 + l16) * 128;
    const int cK0 = (((0 * 4 + lk) ^ (l16 & 7)) << 4);
    const int cK1 = (((1 * 4 + lk) ^ (l16 & 7)) << 4);

    f32x4 acc[8][4] = {};

#define STAGE(ptr, region, tile) do {                                       \
    const uint4* s_ = (ptr) + (size_t)(tile) * 8;                           \
    char* l_ = ldsStage + (((tile) & 1) * 65536 + (region));                \
    gload16(s_, l_);                                                        \
    gload16(s_ + 6144, l_ + 8192);                                          \
} while (0)

#define LDA(d, fm, k) (*(const bf16x8*)(smem + (d) * 65536 + aBase + (fm) * 2048 + cK##k))
#define LDB(d, j,  k) (*(const bf16x8*)(smem + (d) * 65536 + bBase + (j)  * 2048 + cK##k))

#define PHASE(d, p, STAGES, TAILW) do {                                     \
    bf16x8 a00 = LDA(d, 2*(p),     0), a01 = LDA(d, 2*(p),     1);          \
    bf16x8 a10 = LDA(d, 2*(p) + 1, 0), a11 = LDA(d, 2*(p) + 1, 1);          \
    if ((p) == 0) {                                                         \
        bF[0][0] = LDB(d, 0, 0); bF[0][1] = LDB(d, 0, 1);                   \
        bF[1][0] = LDB(d, 1, 0); bF[1][1] = LDB(d, 1, 1);                   \
        bF[2][0] = LDB(d, 2, 0); bF[2][1] = LDB(d, 2, 1);                   \
        bF[3][0] = LDB(d, 3, 0); bF[3][1] = LDB(d, 3, 1);                   \
    }                                                                       \
    STAGES;                                                                 \
    __builtin_amdgcn_s_barrier();                                           \
    asm volatile("s_waitcnt lgkmcnt(0)" ::: "memory");                      \
    __builtin_amdgcn_sched_barrier(0);                                      \
    __builtin_amdgcn_s_setprio(1);                                          \
    _Pragma("unroll") for (int j_ = 0; j_ < 4; j_++)                        \
        acc[2*(p)][j_]     = MF(a00, bF[j_][0], acc[2*(p)][j_]);            \
    _Pragma("unroll") for (int j_ = 0; j_ < 4; j_++)                        \
        acc[2*(p) + 1][j_] = MF(a10, bF[j_][0], acc[2*(p) + 1][j_]);        \
    _Pragma("unroll") for (int j_ = 0; j_ < 4; j_++)                        \
        acc[2*(p)][j_]     = MF(a01, bF[j_][1], acc[2*(p)][j_]);            \
    _Pragma("unroll") for (int j_ = 0; j_ < 4; j_++)                        \
        acc[2*(p) + 1][j_] = MF(a11, bF[j_][1], acc[2*(p) + 1][j_]);        \
    __builtin_amdgcn_s_setprio(0);                                          \
    TAILW;                                                                  \
    __builtin_amdgcn_s_barrier();                                           \
    __builtin_amdgcn_sched_barrier(0);                                      \
} while (0)

#define TILE_STD(d, u) {                                                    \
    bf16x8 bF[4][2];                                                        \
    PHASE(d, 0, STAGE(pA0, 0,     (u) + 1), );                              \
    PHASE(d, 1, STAGE(pA1, 16384, (u) + 1), );                              \
    PHASE(d, 2, STAGE(pB0, 32768, (u) + 2), );                              \
    PHASE(d, 3, STAGE(pB1, 49152, (u) + 2),                                 \
          asm volatile("s_waitcnt vmcnt(4)" ::: "memory"));                 \
}
#define TILE_T10(d, u) {                                                    \
    bf16x8 bF[4][2];                                                        \
    PHASE(d, 0, STAGE(pA0, 0,     (u) + 1), );                              \
    PHASE(d, 1, STAGE(pA1, 16384, (u) + 1), );                              \
    PHASE(d, 2, , );                                                        \
    PHASE(d, 3, ,                                                           \
          asm volatile("s_waitcnt vmcnt(0)" ::: "memory"));                 \
}
#define TILE_T11(d) {                                                       \
    bf16x8 bF[4][2];                                                        \
    PHASE(d, 0, , );                                                        \
    PHASE(d, 1, , );                                                        \
    PHASE(d, 2, , );                                                        \
    PHASE(d, 3, , );                                                        \
}

    // prologue: tile 0 (A+B) + tile 1 (B only); A(1) staged during tile 0
    STAGE(pA0, 0, 0);     STAGE(pA1, 16384, 0);
    STAGE(pB0, 32768, 0); STAGE(pB1, 49152, 0);
    STAGE(pB0, 32768, 1); STAGE(pB1, 49152, 1);
    asm volatile("s_waitcnt vmcnt(4)" ::: "memory");
    __builtin_amdgcn_s_barrier();
    __builtin_amdgcn_sched_barrier(0);

    for (int u = 0; u < 10; u += 2) {
        TILE_STD(0, u);
        TILE_STD(1, u + 1);
    }
    TILE_T10(0, 10);
    TILE_T11(1);

#undef TILE_STD
#undef TILE_T10
#undef TILE_T11
#undef PHASE
#undef LDA
#undef LDB
#undef STAGE

    // epilogue: bias + bf16 store
#pragma unroll
    for (int fm = 0; fm < 8; fm++) {
#pragma unroll
        for (int j = 0; j < 4; j++) {
            int col = nt * 256 + wn * 64 + j * 16 + l16;
            float bc = bias[col];
#pragma unroll
            for (int q = 0; q < 4; q++) {
                int row = mt * 256 + wm * 128 + fm * 16 + lk * 4 + q;
                C[(size_t)row * N + col] = f2bf(acc[fm][j][q] + bc);
            }
        }
    }
}

// ---------------- slot GEMM: out[8192][121] = word[8192][768] * slotW[128][768]^T
__global__ __launch_bounds__(256) void gemm_slot(
    const uint4* __restrict__ A,    // [8192][96]
    const uint4* __restrict__ Bm,   // [128][96]
    const float* __restrict__ bias, // [121]
    float* __restrict__ Cf)         // [8192][121] f32
{
    __shared__ uint4 sA[256];   // 64 rows
    __shared__ uint4 sB[512];   // 128 rows
    const int K8 = 96;

    int mt = blockIdx.x;
    int t = threadIdx.x;
    int lane = t & 63, wave = t >> 6;
    int wm = wave >> 1, wn = wave & 1;
    int l16 = lane & 15, lk = lane >> 4;

    int srow = lane >> 2, schk = lane & 3;
    const uint4* Ag  = A + (size_t)(mt * 64 + wave * 16 + srow) * K8 + schk;
    const uint4* Bg0 = Bm + (size_t)(wave * 32 + srow) * K8 + schk;
    const uint4* Bg1 = Bg0 + (size_t)16 * K8;
    uint4* sAp = &sA[wave * 64];
    uint4* sB0 = &sB[wave * 128];
    uint4* sB1 = &sB[wave * 128 + 64];

    f32x4 zero = {0.f, 0.f, 0.f, 0.f};
    f32x4 acc[2][4];
#pragma unroll
    for (int i = 0; i < 2; i++)
#pragma unroll
        for (int j = 0; j < 4; j++) acc[i][j] = zero;

    for (int k0 = 0; k0 < K8; k0 += 4) {
        gload16(Ag + k0, sAp);
        gload16(Bg0 + k0, sB0);
        gload16(Bg1 + k0, sB1);
        __syncthreads();

        bf16x8 af[2], bfr[4];
#pragma unroll
        for (int i = 0; i < 2; i++)
            af[i] = *reinterpret_cast<const bf16x8*>(&sA[(wm * 32 + i * 16 + l16) * 4 + lk]);
#pragma unroll
        for (int j = 0; j < 4; j++)
            bfr[j] = *reinterpret_cast<const bf16x8*>(&sB[(wn * 64 + j * 16 + l16) * 4 + lk]);
#pragma unroll
        for (int i = 0; i < 2; i++)
#pragma unroll
            for (int j = 0; j < 4; j++)
                acc[i][j] = MF(af[i], bfr[j], acc[i][j]);
        __syncthreads();
    }

#pragma unroll
    for (int i = 0; i < 2; i++) {
#pragma unroll
        for (int j = 0; j < 4; j++) {
            int col = wn * 64 + j * 16 + l16;
            if (col < NSLOT) {
                float bc = bias[col];
#pragma unroll
                for (int q = 0; q < 4; q++) {
                    int row = mt * 64 + wm * 32 + i * 16 + lk * 4 + q;
                    Cf[(size_t)row * NSLOT + col] = acc[i][j][q] + bc;
                }
            }
        }
    }
}

// ---------------- attention: one wave per (b,w) word unit ----------------
__global__ __launch_bounds__(256) void attn_kernel(
    const unsigned short* __restrict__ QKV,  // [B*S][2304] bf16: Q|K|V
    const float* __restrict__ res_all,       // [B*S][768] f32
    const int* __restrict__ starts,
    const int* __restrict__ lens,
    unsigned short* __restrict__ word)       // [B*W][768] bf16
{
    // chunked XCD swizzle: 2048 blocks = 8 x 256 -> one batch's blocks stay on one XCD
    int bid = blockIdx.x;
    bid = (bid & 7) * 256 + (bid >> 3);
    int gw = bid * 4 + (threadIdx.x >> 6);           // 0..8191
    int lane = threadIdx.x & 63;
    int b = gw >> 8;                                 // W=256
    int s0 = starts[gw];
    int sl = lens[gw];                               // 1..7, wave-uniform
    int h0 = lane * 12;                              // each lane owns 12 h's

    const size_t rowQ = (size_t)(b * SS + s0) * 2304;
    float q[12];
#pragma unroll
    for (int c = 0; c < 3; c++) {
        ushort4 u = *reinterpret_cast<const ushort4*>(&QKV[rowQ + h0 + c * 4]);
        q[c * 4 + 0] = bf2f(u.x); q[c * 4 + 1] = bf2f(u.y);
        q[c * 4 + 2] = bf2f(u.z); q[c * 4 + 3] = bf2f(u.w);
    }

    float scores[8];
#pragma unroll
    for (int k = 0; k < LL; k++) {
        if (k > sl) break;                            // uniform branch
        int s = s0 + k; if (s > SS - 1) s = SS - 1;
        const size_t rowK = (size_t)(b * SS + s) * 2304 + HH;
        float partial = 0.f;
#pragma unroll
        for (int c = 0; c < 3; c++) {
            ushort4 u = *reinterpret_cast<const ushort4*>(&QKV[rowK + h0 + c * 4]);
            partial += q[c * 4 + 0] * bf2f(u.x) + q[c * 4 + 1] * bf2f(u.y)
                     + q[c * 4 + 2] * bf2f(u.z) + q[c * 4 + 3] * bf2f(u.w);
        }
#pragma unroll
        for (int off = 32; off > 0; off >>= 1) partial += __shfl_xor(partial, off);
        scores[k] = partial;
    }

    float m = -1e30f;
    for (int k = 0; k < LL; k++) if (k <= sl && scores[k] > m) m = scores[k];
    float p[8], ssum = 0.f;
    for (int k = 0; k < LL; k++) {
        p[k] = (k <= sl) ? __expf(scores[k] - m) : 0.f;
        ssum += p[k];
    }
    float inv = 1.f / ssum;

    float acc[12];
#pragma unroll
    for (int i = 0; i < 12; i++) acc[i] = 0.f;
    for (int k = 0; k < LL; k++) {
        if (k > sl) break;                            // uniform
        int s = s0 + k; if (s > SS - 1) s = SS - 1;
        const size_t rowV = (size_t)(b * SS + s) * 2304 + 2 * HH;
        float wk = p[k] * inv;
#pragma unroll
        for (int c = 0; c < 3; c++) {
            ushort4 u = *reinterpret_cast<const ushort4*>(&QKV[rowV + h0 + c * 4]);
            acc[c * 4 + 0] += wk * bf2f(u.x); acc[c * 4 + 1] += wk * bf2f(u.y);
            acc[c * 4 + 2] += wk * bf2f(u.z); acc[c * 4 + 3] += wk * bf2f(u.w);
        }
    }

    const float* frow = res_all + (size_t)(b * SS + s0) * HH;
    float fst[12];
#pragma unroll
    for (int c = 0; c < 3; c++) {
        float4 f = *reinterpret_cast<const float4*>(&frow[h0 + c * 4]);
        fst[c * 4 + 0] = f.x; fst[c * 4 + 1] = f.y; fst[c * 4 + 2] = f.z; fst[c * 4 + 3] = f.w;
    }

    unsigned short* wrow = word + (size_t)gw * HH + h0;
#pragma unroll
    for (int c = 0; c < 3; c++) {
        ushort4 o;
        float v0, v1, v2, v3;
        if (sl == 1) { v0 = fst[c*4+0]; v1 = fst[c*4+1]; v2 = fst[c*4+2]; v3 = fst[c*4+3]; }
        else { v0 = acc[c*4+0] + fst[c*4+0]; v1 = acc[c*4+1] + fst[c*4+1];
               v2 = acc[c*4+2] + fst[c*4+2]; v3 = acc[c*4+3] + fst[c*4+3]; }
        o.x = f2bf(v0); o.y = f2bf(v1); o.z = f2bf(v2); o.w = f2bf(v3);
        *reinterpret_cast<ushort4*>(&wrow[c * 4]) = o;
    }
}

// ---------------- res_id: tiny f32 GEMV ----------------
__global__ __launch_bounds__(256) void resid_kernel(
    const float* __restrict__ res, const float* __restrict__ w,
    const float* __restrict__ bias, float* __restrict__ out) {
    int bb = blockIdx.x;
    int t = threadIdx.x, lane = t & 63, wave = t >> 6;
    __shared__ float sres[HH];
    for (int i = t; i < HH; i += 256) sres[i] = res[bb * HH + i];
    __syncthreads();
    for (int o = wave; o < NINTENT; o += 4) {
        float s = 0.f;
        for (int i = lane; i < HH; i += 64) s += sres[i] * w[o * HH + i];
#pragma unroll
        for (int off = 32; off > 0; off >>= 1) s += __shfl_xor(s, off);
        if (lane == 0) out[bb * NINTENT + o] = s + bias[o];
    }
}

// ---------------- launch ----------------
extern "C" void kernel_launch(void* const* d_in, const int* in_sizes, int n_in,
                              void* d_out, int out_size, void* d_ws, size_t ws_size,
                              hipStream_t stream) {
    const float* res_all    = (const float*)d_in[0];
    const float* res        = (const float*)d_in[1];
    const int*   starts     = (const int*)d_in[2];
    const int*   lens       = (const int*)d_in[3];
    const float* Wsq_w      = (const float*)d_in[4];
    const float* Wsq_b      = (const float*)d_in[5];
    const float* Wsk_w      = (const float*)d_in[6];
    const float* Wsk_b      = (const float*)d_in[7];
    const float* Wsv_w      = (const float*)d_in[8];
    const float* Wsv_b      = (const float*)d_in[9];
    const float* lin_id_w   = (const float*)d_in[10];
    const float* lin_id_b   = (const float*)d_in[11];
    const float* lin_slot_w = (const float*)d_in[12];
    const float* lin_slot_b = (const float*)d_in[13];
    float* out = (float*)d_out;

    char* ws = (char*)d_ws;
    unsigned short* Abf   = (unsigned short*)(ws + 0);          // 16384x768 bf16
    unsigned short* Wcat  = (unsigned short*)(ws + 25165824);   // 2304x768 bf16
    unsigned short* QKV   = (unsigned short*)(ws + 28704768);   // 16384x2304 bf16
    unsigned short* wordb = (unsigned short*)(ws + 104202240);  // 8192x768 bf16
    unsigned short* slotW = (unsigned short*)(ws + 116785152);  // 128x768 bf16
    float*          biascat = (float*)(ws + 116981760);         // 2304 f32

    // allow 128 KiB dynamic LDS for gemm_qkv3 (host-side, capture-safe)
    hipFuncSetAttribute((const void*)gemm_qkv3,
                        hipFuncAttributeMaxDynamicSharedMemorySize, 131072);

    cast_f32_bf16<<<4096, 256, 0, stream>>>((const float4*)res_all, (ushort4*)Abf,
                                            (BB * SS * HH) / 4);

    prep_kernel<<<1827, 256, 0, stream>>>(
        (const float4*)Wsq_w, (const float4*)Wsk_w, (const float4*)Wsv_w,
        (ushort4*)Wcat, (const float4*)lin_slot_w, (ushort4*)slotW,
        Wsq_b, Wsk_b, Wsv_b, biascat);

    // QKV GEMM: M=16384 (64 m-tiles), N=2304 (9 n-tiles) -> 576 blocks
    gemm_qkv3<<<576, 512, 131072, stream>>>((const uint4*)Abf, (const uint4*)Wcat,
                                            biascat, QKV);

    // attention: 8192 word units, 1 wave each
    attn_kernel<<<2048, 256, 0, stream>>>(QKV, res_all, starts, lens, wordb);

    // slot GEMM: M=8192 (128 tiles of 64), N=128 (121 real cols)
    gemm_slot<<<128, 256, 0, stream>>>((const uint4*)wordb, (const uint4*)slotW,
                                       lin_slot_b, out + 832);

    // res_id
    resid_kernel<<<BB, 256, 0, stream>>>(res, lin_id_w, lin_id_b, out);
}